// Round 5
// baseline (90.985 us; speedup 1.0000x reference)
//
#include <hip/hip_runtime.h>

// HEAQNetwork: batched 4-qubit, 3-layer circuit. Fully reduced form:
//  * layer 1 = product state; layer-1 CNOT chain folded into the build
//    permutation; layer-2 CNOT chain folded into layer-3 pair indices and
//    measurement signs (R4). All CNOTs cost zero instructions.
//  * A/B split (R5): after the fold, no gate or measurement sign touches
//    bit 0 of the flat index, so even/odd amplitudes form two independent
//    8-amp complex states evolving under identical gates.
//  * 2 batch elements per thread (b and b+B/2): amortizes setup, gives 4
//    independent FMA chains per wave for latency hiding.
//
// k-space (k = flat_index >> 1): L2 gates use masks 4/2/1; L3 q0 acts on
// pairs (k, k^6) lo={0,1,2,3}, L3 q1 on (k, k^3) lo={0,1,6,7}.
// z0 sign = -(k&4), z1 sign = -(k&2).

__device__ __forceinline__ float rdlane(float x, int l) {
    return __int_as_float(__builtin_amdgcn_readlane(__float_as_int(x), l));
}

// RX [[c,-is],[-is,c]] over explicit 4-pair lists on an 8-amp state
__device__ __forceinline__ void rx8(float (&re)[8], float (&im)[8],
                                    float c, float s,
                                    const int (&lo)[4], const int (&hi)[4]) {
#pragma unroll
    for (int t = 0; t < 4; ++t) {
        const int i = lo[t], j = hi[t];
        float a0r = re[i], a0i = im[i], a1r = re[j], a1i = im[j];
        re[i] = __builtin_fmaf(c, a0r,  s * a1i);
        im[i] = __builtin_fmaf(c, a0i, -(s * a1r));
        re[j] = __builtin_fmaf(c, a1r,  s * a0i);
        im[j] = __builtin_fmaf(c, a1i, -(s * a0r));
    }
}

// RY [[c,-s],[s,c]] (real) over explicit 4-pair lists
__device__ __forceinline__ void ry8(float (&re)[8], float (&im)[8],
                                    float c, float s,
                                    const int (&lo)[4], const int (&hi)[4]) {
#pragma unroll
    for (int t = 0; t < 4; ++t) {
        const int i = lo[t], j = hi[t];
        float a0r = re[i], a0i = im[i], a1r = re[j], a1i = im[j];
        re[i] = __builtin_fmaf(c, a0r, -(s * a1r));
        im[i] = __builtin_fmaf(c, a0i, -(s * a1i));
        re[j] = __builtin_fmaf(s, a0r,   c * a1r);
        im[j] = __builtin_fmaf(s, a0i,   c * a1i);
    }
}

__global__ __launch_bounds__(256) void heaq_kernel(
    const float4* __restrict__ x4,
    const float*  __restrict__ w_input,
    const float*  __restrict__ weights,
    const float*  __restrict__ w_output,
    float2*       __restrict__ out2,
    int B)
{
    const int lane = threadIdx.x & 63;

    // batch-uniform RY half-angle sincos: lanes 0..11 compute, readlane
    // broadcasts to SGPRs (before bounds check so all lanes are valid).
    const float K = 0.07957747154594767f;  // 1/(4*pi)
    float wv  = weights[lane < 12 ? lane : 0];
    float rev = __builtin_amdgcn_fractf(wv * K);
    float sn  = __builtin_amdgcn_sinf(rev);
    float cn  = __builtin_amdgcn_cosf(rev);

    const float cy0 = rdlane(cn, 0), sy0 = rdlane(sn, 0);
    const float cy1 = rdlane(cn, 1), sy1 = rdlane(sn, 1);
    const float cy2 = rdlane(cn, 2), sy2 = rdlane(sn, 2);
    const float cy3 = rdlane(cn, 3), sy3 = rdlane(sn, 3);
    const float cy4 = rdlane(cn, 4), sy4 = rdlane(sn, 4);
    const float cy5 = rdlane(cn, 5), sy5 = rdlane(sn, 5);
    const float cy6 = rdlane(cn, 6), sy6 = rdlane(sn, 6);
    const float cy8 = rdlane(cn, 8), sy8 = rdlane(sn, 8);
    const float cy9 = rdlane(cn, 9), sy9 = rdlane(sn, 9);

    const int H = B >> 1;
    const int b = blockIdx.x * 256 + threadIdx.x;
    if (b >= H) return;

    const float wi0 = w_input[0], wi1 = w_input[1];
    const float wi2 = w_input[2], wi3 = w_input[3];
    const float hw0 = 0.5f * w_output[0], hw1 = 0.5f * w_output[1];

    // pair lists (k-space)
    static constexpr int m4_lo[4] = {0,1,2,3}, m4_hi[4] = {4,5,6,7};
    static constexpr int m2_lo[4] = {0,1,4,5}, m2_hi[4] = {2,3,6,7};
    static constexpr int m1_lo[4] = {0,2,4,6}, m1_hi[4] = {1,3,5,7};
    static constexpr int x6_lo[4] = {0,1,2,3}, x6_hi[4] = {6,7,4,5};
    static constexpr int x3_lo[4] = {0,1,6,7}, x3_hi[4] = {3,2,5,4};
    // build: A[k] = p3[hk[k]] * v3[k&1], B[k] = p3[hk[k]] * v3[1-(k&1)]
    static constexpr int hk[8] = {0,1,3,2,6,7,5,4};

    const float cys[4] = {cy0, cy1, cy2, cy3};
    const float sys[4] = {sy0, sy1, sy2, sy3};

    float Ar[2][8], Ai[2][8], Br[2][8], Bi[2][8];
    float cx[2][3], sx[2][3];   // only qubits 0..2 needed after layer 1

#pragma unroll
    for (int e = 0; e < 2; ++e) {
        const float4 xv = x4[e ? b + H : b];
        const float xs[4] = {xv.x * wi0, xv.y * wi1, xv.z * wi2, xv.w * wi3};

        // half-angle cos/sin of theta = atan(u)
        float cq[4], sq[4];
#pragma unroll
        for (int q = 0; q < 4; ++q) {
            float u = xs[q];
            float r = __builtin_amdgcn_rsqf(__builtin_fmaf(u, u, 1.0f));
            float c = __builtin_amdgcn_sqrtf(__builtin_fmaf(0.5f, r, 0.5f));
            cq[q] = c;
            sq[q] = 0.5f * u * r * __builtin_amdgcn_rcpf(c);
        }
#pragma unroll
        for (int q = 0; q < 3; ++q) { cx[e][q] = cq[q]; sx[e][q] = sq[q]; }

        // layer-1 product state: v_q = RY RX |0>
        float vr[4][2], vi[4][2];
#pragma unroll
        for (int q = 0; q < 4; ++q) {
            vr[q][0] = cys[q] * cq[q];
            vi[q][0] = sys[q] * sq[q];
            vr[q][1] = sys[q] * cq[q];
            vi[q][1] = -cys[q] * sq[q];
        }
        float p2r[4], p2i[4];
#pragma unroll
        for (int i = 0; i < 4; ++i) {
            const int a = i >> 1, c = i & 1;
            p2r[i] = __builtin_fmaf(vr[0][a], vr[1][c], -(vi[0][a] * vi[1][c]));
            p2i[i] = __builtin_fmaf(vr[0][a], vi[1][c],   vi[0][a] * vr[1][c]);
        }
        float p3r[8], p3i[8];
#pragma unroll
        for (int i = 0; i < 8; ++i) {
            const int h = i >> 1, c = i & 1;
            p3r[i] = __builtin_fmaf(p2r[h], vr[2][c], -(p2i[h] * vi[2][c]));
            p3i[i] = __builtin_fmaf(p2r[h], vi[2][c],   p2i[h] * vr[2][c]);
        }
#pragma unroll
        for (int k = 0; k < 8; ++k) {
            const int h = hk[k], ta = k & 1, tb = ta ^ 1;
            Ar[e][k] = __builtin_fmaf(p3r[h], vr[3][ta], -(p3i[h] * vi[3][ta]));
            Ai[e][k] = __builtin_fmaf(p3r[h], vi[3][ta],   p3i[h] * vr[3][ta]);
            Br[e][k] = __builtin_fmaf(p3r[h], vr[3][tb], -(p3i[h] * vi[3][tb]));
            Bi[e][k] = __builtin_fmaf(p3r[h], vi[3][tb],   p3i[h] * vr[3][tb]);
        }
    }

    // ---- Layer 2 (k-space masks 4/2/1) + Layer 3 (folded pairs) ----
#pragma unroll
    for (int e = 0; e < 2; ++e) {
        rx8(Ar[e], Ai[e], cx[e][0], sx[e][0], m4_lo, m4_hi);
        rx8(Br[e], Bi[e], cx[e][0], sx[e][0], m4_lo, m4_hi);
        rx8(Ar[e], Ai[e], cx[e][1], sx[e][1], m2_lo, m2_hi);
        rx8(Br[e], Bi[e], cx[e][1], sx[e][1], m2_lo, m2_hi);
        rx8(Ar[e], Ai[e], cx[e][2], sx[e][2], m1_lo, m1_hi);
        rx8(Br[e], Bi[e], cx[e][2], sx[e][2], m1_lo, m1_hi);
        ry8(Ar[e], Ai[e], cy4, sy4, m4_lo, m4_hi);
        ry8(Br[e], Bi[e], cy4, sy4, m4_lo, m4_hi);
        ry8(Ar[e], Ai[e], cy5, sy5, m2_lo, m2_hi);
        ry8(Br[e], Bi[e], cy5, sy5, m2_lo, m2_hi);
        ry8(Ar[e], Ai[e], cy6, sy6, m1_lo, m1_hi);
        ry8(Br[e], Bi[e], cy6, sy6, m1_lo, m1_hi);

        rx8(Ar[e], Ai[e], cx[e][0], sx[e][0], x6_lo, x6_hi);
        rx8(Br[e], Bi[e], cx[e][0], sx[e][0], x6_lo, x6_hi);
        rx8(Ar[e], Ai[e], cx[e][1], sx[e][1], x3_lo, x3_hi);
        rx8(Br[e], Bi[e], cx[e][1], sx[e][1], x3_lo, x3_hi);
        ry8(Ar[e], Ai[e], cy8, sy8, x6_lo, x6_hi);
        ry8(Br[e], Bi[e], cy8, sy8, x6_lo, x6_hi);
        ry8(Ar[e], Ai[e], cy9, sy9, x3_lo, x3_hi);
        ry8(Br[e], Bi[e], cy9, sy9, x3_lo, x3_hi);
    }

    // ---- Measurement: z0 = -sum(k&4), z1 = -sum(k&2) ----
#pragma unroll
    for (int e = 0; e < 2; ++e) {
        float pk[8];
#pragma unroll
        for (int k = 0; k < 8; ++k) {
            float t = __builtin_fmaf(Ar[e][k], Ar[e][k], Ai[e][k] * Ai[e][k]);
            t = __builtin_fmaf(Br[e][k], Br[e][k], t);
            pk[k] = __builtin_fmaf(Bi[e][k], Bi[e][k], t);
        }
        float G0 = pk[0] + pk[1];   // k bits(2,1) = 00
        float G1 = pk[2] + pk[3];   // 01
        float G2 = pk[4] + pk[5];   // 10
        float G3 = pk[6] + pk[7];   // 11
        float z0 = (G0 + G1) - (G2 + G3);
        float z1 = (G0 + G2) - (G1 + G3);
        out2[e ? b + H : b] = make_float2(__builtin_fmaf(z0, hw0, hw0),
                                          __builtin_fmaf(z1, hw1, hw1));
    }
}

extern "C" void kernel_launch(void* const* d_in, const int* in_sizes, int n_in,
                              void* d_out, int out_size, void* d_ws, size_t ws_size,
                              hipStream_t stream) {
    const float* x        = (const float*)d_in[0];
    const float* w_input  = (const float*)d_in[1];
    const float* weights  = (const float*)d_in[2];
    const float* w_output = (const float*)d_in[3];
    float* out = (float*)d_out;

    const int B = in_sizes[0] / 4;
    const int H = B >> 1;

    heaq_kernel<<<(H + 255) / 256, 256, 0, stream>>>(
        (const float4*)x, w_input, weights, w_output, (float2*)out, B);
}

// Round 6
// 74.362 us; speedup vs baseline: 1.2235x; 1.2235x over previous
//
#include <hip/hip_runtime.h>

// HEAQNetwork via full Heisenberg (Pauli) propagation — zero state evolution.
// z0 = <Z0>, z1 = <Z0 Z1> (L3 CNOTs absorbed). Pulled back through L3 gates
// (n,p vectors), L2 CNOT chain (9-term Pauli expansion), L2 gates (D-matrix
// rows), L1 CNOT chain (compile-time Psi images), evaluated on the product
// state G1|0> via per-qubit Bloch vectors s_q. All Pauli algebra is
// compile-time; runtime = ~200 fp32 ops/element.
//
// Derivation checked: D rows by direct 2x2 conjugation; C2 expansion
// Hermitian term-by-term; identity & two nontrivial hand cases match.

__device__ __forceinline__ float rdlane(float x, int l) {
    return __int_as_float(__builtin_amdgcn_readlane(__float_as_int(x), l));
}

__global__ __launch_bounds__(256) void heaq_kernel(
    const float4* __restrict__ x4,
    const float*  __restrict__ w_input,
    const float*  __restrict__ weights,
    const float*  __restrict__ w_output,
    float2*       __restrict__ out2,
    int B)
{
    const int lane = threadIdx.x & 63;

    // full-angle sincos of the 12 batch-uniform weights via lanes 0..11
    const float K2 = 0.15915494309189535f;  // 1/(2*pi)
    float wv  = weights[lane < 12 ? lane : 0];
    float rev = __builtin_amdgcn_fractf(wv * K2);
    float sn  = __builtin_amdgcn_sinf(rev);
    float cn  = __builtin_amdgcn_cosf(rev);

    // layer-0 (s_q Bloch): q0..3 ; layer-1 (D rows): q0..2 ; layer-2: q0,q1
    const float sw00 = rdlane(sn, 0), cw00 = rdlane(cn, 0);
    const float sw01 = rdlane(sn, 1), cw01 = rdlane(cn, 1);
    const float sw02 = rdlane(sn, 2), cw02 = rdlane(cn, 2);
    const float sw03 = rdlane(sn, 3);
    const float sB0  = rdlane(sn, 4), cB0  = rdlane(cn, 4);
    const float sB1  = rdlane(sn, 5), cB1  = rdlane(cn, 5);
    const float sB2  = rdlane(sn, 6), cB2  = rdlane(cn, 6);
    const float sC0  = rdlane(sn, 8), cC0  = rdlane(cn, 8);
    const float sC1  = rdlane(sn, 9), cC1  = rdlane(cn, 9);

    const int b = blockIdx.x * 256 + threadIdx.x;
    if (b >= B) return;

    // ---- RX angles: theta_q = atan(u), need full-angle cos/sin only:
    // ca = rsqrt(1+u^2), sa = u*ca ----
    const float4 xv = x4[b];
    const float us[4] = {xv.x * w_input[0], xv.y * w_input[1],
                         xv.z * w_input[2], xv.w * w_input[3]};
    float ca[4], sa[4];
#pragma unroll
    for (int q = 0; q < 4; ++q) {
        float u = us[q];
        float r = __builtin_amdgcn_rsqf(__builtin_fmaf(u, u, 1.0f));
        ca[q] = r;
        sa[q] = u * r;
    }

    // ---- Bloch vectors of chi_q = RY(w0q) RX(a_q) |0> ----
    const float s0x = sw00 * ca[0], s0y = -sa[0], s0z = cw00 * ca[0];
    const float s1x = sw01 * ca[1], s1y = -sa[1], s1z = cw01 * ca[1];
    const float s2x = sw02 * ca[2], s2y = -sa[2], s2z = cw02 * ca[2];
    const float s3x = sw03 * ca[3];

    // ---- D rows (V_q = RY(w1q) RX(a_q) conjugation), and n,p (layer 3) ----
    // D[x]=(cB, sB*sa, sB*ca); D[y]=(0, ca, -sa); D[z]=(-sB, cB*sa, cB*ca)
    const float ax = cB0, ay = sB0 * sa[0], az = sB0 * ca[0];
    const float           by = ca[0],       bz = -sa[0];
    const float dx = -sB0, dy = cB0 * sa[0], dz = cB0 * ca[0];
    const float ex = cB1, ey = sB1 * sa[1], ez = sB1 * ca[1];
    const float           fy = ca[1],       fz = -sa[1];
    const float gx = -sB1, gy = cB1 * sa[1], gz = cB1 * ca[1];
    const float hx = cB2, hy = sB2 * sa[2], hz = sB2 * ca[2];
    const float nx = -sC0, ny = cC0 * sa[0], nz = cC0 * ca[0];
    const float px = -sC1, py = cC1 * sa[1], pz = cC1 * ca[1];

    // ---- shared precomputes ----
    const float t01   = s0z * s1x;
    const float t0z1y = s0z * s1y;
    const float t0z1z = s0z * s1z;
    const float m1 = s2y * s3x, m2 = s2x * s3x, m3 = s2z * s3x;
    const float RCh = __builtin_fmaf(hy, m1, hz * s2z);  // <(h.s)_2 strings>
    const float RDh = hx * m2;
    const float hx3 = hx * s3x;
    const float q1t = __builtin_fmaf(hz, s2y, -(hy * m3));

    // per-v0 bilinears A = vx*s0x + vy*s0y, Bq = vx*s0y - vy*s0x
    const float Aa = __builtin_fmaf(ax, s0x, ay * s0y);
    const float Ba = __builtin_fmaf(ax, s0y, -(ay * s0x));
    const float Ab = by * s0y;         // bx = 0
    const float Bb = -(by * s0x);
    const float Ad = __builtin_fmaf(dx, s0x, dy * s0y);
    const float Bd = __builtin_fmaf(dx, s0y, -(dy * s0x));

    // ---- z0 = E01(u, e) + nz * E0(d),  u = nx*a + ny*b ----
    const float ux = nx * ax;
    const float uy = __builtin_fmaf(nx, ay, ny * by);
    const float uz = __builtin_fmaf(nx, az, ny * bz);
    const float Au = __builtin_fmaf(ux, s0x, uy * s0y);
    const float Bu = __builtin_fmaf(ux, s0y, -(uy * s0x));
    const float E01u = (ex * s2x) * __builtin_fmaf(uz, t01, Au)
                     + (ey * s2x) * __builtin_fmaf(Bu, s1z, uz * s1y)
                     + ez * __builtin_fmaf(uz, s1z, -(Bu * s1y));
    const float E0d = __builtin_fmaf(Ad, s1x, dz * s0z);
    const float z0 = __builtin_fmaf(nz, E0d, E01u);

    // ---- z1 pieces ----
    // E02(v0, h) = RCh*(-B*s1y + vz*s1z) + RDh*(A*s1x + vz*s0z)
    const float E02a = RCh * __builtin_fmaf(az, s1z, -(Ba * s1y))
                     + RDh * __builtin_fmaf(Aa, s1x, az * s0z);
    const float E02b = RCh * __builtin_fmaf(bz, s1z, -(Bb * s1y))
                     + RDh * __builtin_fmaf(Ab, s1x, bz * s0z);

    // R-coefficients for (g,h) and (e,h)
    const float RAg = __builtin_fmaf(gx, hx3, gy * q1t);
    const float RBg = __builtin_fmaf(gy, hx3, -(gx * q1t));
    const float RCg = gz * RDh;
    const float RDg = gz * RCh;
    const float RAe = __builtin_fmaf(ex, hx3, ey * q1t);
    const float RBe = __builtin_fmaf(ey, hx3, -(ex * q1t));
    const float RCe = ez * RDh;
    const float RDe = ez * RCh;

    // E012(v0; RA,RB,RC,RD) = RA*(A + vz*t01) + RB*(B*s1z + vz*s1y)
    //                       + RC*(-B*s1y + vz*s1z) + RD*(A*s1x + vz*s0z)
    const float E012b = RAg * __builtin_fmaf(bz, t01, Ab)
                      + RBg * __builtin_fmaf(Bb, s1z, bz * s1y)
                      + RCg * __builtin_fmaf(bz, s1z, -(Bb * s1y))
                      + RDg * __builtin_fmaf(Ab, s1x, bz * s0z);
    const float E012a = RAg * __builtin_fmaf(az, t01, Aa)
                      + RBg * __builtin_fmaf(Ba, s1z, az * s1y)
                      + RCg * __builtin_fmaf(az, s1z, -(Ba * s1y))
                      + RDg * __builtin_fmaf(Aa, s1x, az * s0z);
    const float E012d = RAe * __builtin_fmaf(dz, t01, Ad)
                      + RBe * __builtin_fmaf(Bd, s1z, dz * s1y)
                      + RCe * __builtin_fmaf(dz, s1z, -(Bd * s1y))
                      + RDe * __builtin_fmaf(Ad, s1x, dz * s0z);

    // E01(v0, f) with fx=0: fy*s2x*(B*s1z + vz*s1y) + fz*(-B*s1y + vz*s1z)
    const float fys2x = fy * s2x;
    const float E01bf = fys2x * __builtin_fmaf(Bb, s1z, bz * s1y)
                      + fz * __builtin_fmaf(bz, s1z, -(Bb * s1y));
    const float E01af = fys2x * __builtin_fmaf(Ba, s1z, az * s1y)
                      + fz * __builtin_fmaf(az, s1z, -(Ba * s1y));

    // E12(f,h) = fy*q1t*s1x + fy*hx3*t0z1y + fz*RDh*t0z1z + fz*RCh
    const float E12fh = (fy * q1t) * s1x + (fy * hx3) * t0z1y
                      + (fz * RDh) * t0z1z + fz * RCh;

    // E1(g) = s2x*(gx*s1x + gy*t0z1y) + gz*t0z1z
    const float E1g = s2x * __builtin_fmaf(gx, s1x, gy * t0z1y) + gz * t0z1z;

    // z1 = nx*(px*E02a + py*E012b - pz*E01bf)
    //    + ny*(px*E02b - py*E012a + pz*E01af)
    //    + nz*(px*E012d + py*E12fh + pz*E1g)
    const float zx = __builtin_fmaf(px, E02a,
                     __builtin_fmaf(py, E012b, -(pz * E01bf)));
    const float zy = __builtin_fmaf(px, E02b,
                     __builtin_fmaf(pz, E01af, -(py * E012a)));
    const float zz = __builtin_fmaf(px, E012d,
                     __builtin_fmaf(py, E12fh, pz * E1g));
    const float z1 = __builtin_fmaf(nx, zx, __builtin_fmaf(ny, zy, nz * zz));

    const float hw0 = 0.5f * w_output[0], hw1 = 0.5f * w_output[1];
    out2[b] = make_float2(__builtin_fmaf(z0, hw0, hw0),
                          __builtin_fmaf(z1, hw1, hw1));
}

extern "C" void kernel_launch(void* const* d_in, const int* in_sizes, int n_in,
                              void* d_out, int out_size, void* d_ws, size_t ws_size,
                              hipStream_t stream) {
    const float* x        = (const float*)d_in[0];
    const float* w_input  = (const float*)d_in[1];
    const float* weights  = (const float*)d_in[2];
    const float* w_output = (const float*)d_in[3];
    float* out = (float*)d_out;

    const int B = in_sizes[0] / 4;

    heaq_kernel<<<(B + 255) / 256, 256, 0, stream>>>(
        (const float4*)x, w_input, weights, w_output, (float2*)out, B);
}

// Round 7
// 73.019 us; speedup vs baseline: 1.2460x; 1.0184x over previous
//
#include <hip/hip_runtime.h>

// HEAQNetwork via full Heisenberg (Pauli) propagation — zero state evolution
// (R6, verified: absmax 0.25). R7: 2 batch elements per thread (b, b+H),
// both float4 loads issued up-front; amortizes the sincos/readlane preamble
// and doubles per-wave memory-level parallelism.

__device__ __forceinline__ float rdlane(float x, int l) {
    return __int_as_float(__builtin_amdgcn_readlane(__float_as_int(x), l));
}

__global__ __launch_bounds__(256) void heaq_kernel(
    const float4* __restrict__ x4,
    const float*  __restrict__ w_input,
    const float*  __restrict__ weights,
    const float*  __restrict__ w_output,
    float2*       __restrict__ out2,
    int B)
{
    const int lane = threadIdx.x & 63;

    // full-angle sincos of the 12 batch-uniform weights via lanes 0..11
    const float K2 = 0.15915494309189535f;  // 1/(2*pi)
    float wv  = weights[lane < 12 ? lane : 0];
    float rev = __builtin_amdgcn_fractf(wv * K2);
    float sn  = __builtin_amdgcn_sinf(rev);
    float cn  = __builtin_amdgcn_cosf(rev);

    const float sw00 = rdlane(sn, 0), cw00 = rdlane(cn, 0);
    const float sw01 = rdlane(sn, 1), cw01 = rdlane(cn, 1);
    const float sw02 = rdlane(sn, 2), cw02 = rdlane(cn, 2);
    const float sw03 = rdlane(sn, 3);
    const float sB0  = rdlane(sn, 4), cB0  = rdlane(cn, 4);
    const float sB1  = rdlane(sn, 5), cB1  = rdlane(cn, 5);
    const float sB2  = rdlane(sn, 6), cB2  = rdlane(cn, 6);
    const float sC0  = rdlane(sn, 8), cC0  = rdlane(cn, 8);
    const float sC1  = rdlane(sn, 9), cC1  = rdlane(cn, 9);

    const int H = B >> 1;
    const int b = blockIdx.x * 256 + threadIdx.x;
    if (b >= H) return;

    const float wi0 = w_input[0], wi1 = w_input[1];
    const float wi2 = w_input[2], wi3 = w_input[3];
    const float hw0 = 0.5f * w_output[0], hw1 = 0.5f * w_output[1];

    // issue both loads before any dependent math
    const float4 xva = x4[b];
    const float4 xvb = x4[b + H];

#pragma unroll
    for (int e = 0; e < 2; ++e) {
        const float4 xv = e ? xvb : xva;
        const float us[4] = {xv.x * wi0, xv.y * wi1, xv.z * wi2, xv.w * wi3};
        float ca[4], sa[4];
#pragma unroll
        for (int q = 0; q < 4; ++q) {
            float u = us[q];
            float r = __builtin_amdgcn_rsqf(__builtin_fmaf(u, u, 1.0f));
            ca[q] = r;
            sa[q] = u * r;
        }

        // Bloch vectors of chi_q = RY(w0q) RX(a_q) |0>
        const float s0x = sw00 * ca[0], s0y = -sa[0], s0z = cw00 * ca[0];
        const float s1x = sw01 * ca[1], s1y = -sa[1], s1z = cw01 * ca[1];
        const float s2x = sw02 * ca[2], s2y = -sa[2], s2z = cw02 * ca[2];
        const float s3x = sw03 * ca[3];

        // D rows (layer-2 conjugation) and n,p (layer 3)
        const float ax = cB0, ay = sB0 * sa[0], az = sB0 * ca[0];
        const float           by = ca[0],       bz = -sa[0];
        const float dx = -sB0, dy = cB0 * sa[0], dz = cB0 * ca[0];
        const float ex = cB1, ey = sB1 * sa[1], ez = sB1 * ca[1];
        const float           fy = ca[1],       fz = -sa[1];
        const float gx = -sB1, gy = cB1 * sa[1], gz = cB1 * ca[1];
        const float hx = cB2, hy = sB2 * sa[2], hz = sB2 * ca[2];
        const float nx = -sC0, ny = cC0 * sa[0], nz = cC0 * ca[0];
        const float px = -sC1, py = cC1 * sa[1], pz = cC1 * ca[1];

        // shared precomputes
        const float t01   = s0z * s1x;
        const float t0z1y = s0z * s1y;
        const float t0z1z = s0z * s1z;
        const float m1 = s2y * s3x, m2 = s2x * s3x, m3 = s2z * s3x;
        const float RCh = __builtin_fmaf(hy, m1, hz * s2z);
        const float RDh = hx * m2;
        const float hx3 = hx * s3x;
        const float q1t = __builtin_fmaf(hz, s2y, -(hy * m3));

        const float Aa = __builtin_fmaf(ax, s0x, ay * s0y);
        const float Ba = __builtin_fmaf(ax, s0y, -(ay * s0x));
        const float Ab = by * s0y;
        const float Bb = -(by * s0x);
        const float Ad = __builtin_fmaf(dx, s0x, dy * s0y);
        const float Bd = __builtin_fmaf(dx, s0y, -(dy * s0x));

        // z0 = E01(u, e) + nz * E0(d),  u = nx*a + ny*b
        const float ux = nx * ax;
        const float uy = __builtin_fmaf(nx, ay, ny * by);
        const float uz = __builtin_fmaf(nx, az, ny * bz);
        const float Au = __builtin_fmaf(ux, s0x, uy * s0y);
        const float Bu = __builtin_fmaf(ux, s0y, -(uy * s0x));
        const float E01u = (ex * s2x) * __builtin_fmaf(uz, t01, Au)
                         + (ey * s2x) * __builtin_fmaf(Bu, s1z, uz * s1y)
                         + ez * __builtin_fmaf(uz, s1z, -(Bu * s1y));
        const float E0d = __builtin_fmaf(Ad, s1x, dz * s0z);
        const float z0 = __builtin_fmaf(nz, E0d, E01u);

        // z1 pieces
        const float E02a = RCh * __builtin_fmaf(az, s1z, -(Ba * s1y))
                         + RDh * __builtin_fmaf(Aa, s1x, az * s0z);
        const float E02b = RCh * __builtin_fmaf(bz, s1z, -(Bb * s1y))
                         + RDh * __builtin_fmaf(Ab, s1x, bz * s0z);

        const float RAg = __builtin_fmaf(gx, hx3, gy * q1t);
        const float RBg = __builtin_fmaf(gy, hx3, -(gx * q1t));
        const float RCg = gz * RDh;
        const float RDg = gz * RCh;
        const float RAe = __builtin_fmaf(ex, hx3, ey * q1t);
        const float RBe = __builtin_fmaf(ey, hx3, -(ex * q1t));
        const float RCe = ez * RDh;
        const float RDe = ez * RCh;

        const float E012b = RAg * __builtin_fmaf(bz, t01, Ab)
                          + RBg * __builtin_fmaf(Bb, s1z, bz * s1y)
                          + RCg * __builtin_fmaf(bz, s1z, -(Bb * s1y))
                          + RDg * __builtin_fmaf(Ab, s1x, bz * s0z);
        const float E012a = RAg * __builtin_fmaf(az, t01, Aa)
                          + RBg * __builtin_fmaf(Ba, s1z, az * s1y)
                          + RCg * __builtin_fmaf(az, s1z, -(Ba * s1y))
                          + RDg * __builtin_fmaf(Aa, s1x, az * s0z);
        const float E012d = RAe * __builtin_fmaf(dz, t01, Ad)
                          + RBe * __builtin_fmaf(Bd, s1z, dz * s1y)
                          + RCe * __builtin_fmaf(dz, s1z, -(Bd * s1y))
                          + RDe * __builtin_fmaf(Ad, s1x, dz * s0z);

        const float fys2x = fy * s2x;
        const float E01bf = fys2x * __builtin_fmaf(Bb, s1z, bz * s1y)
                          + fz * __builtin_fmaf(bz, s1z, -(Bb * s1y));
        const float E01af = fys2x * __builtin_fmaf(Ba, s1z, az * s1y)
                          + fz * __builtin_fmaf(az, s1z, -(Ba * s1y));

        const float E12fh = (fy * q1t) * s1x + (fy * hx3) * t0z1y
                          + (fz * RDh) * t0z1z + fz * RCh;

        const float E1g = s2x * __builtin_fmaf(gx, s1x, gy * t0z1y)
                        + gz * t0z1z;

        const float zx = __builtin_fmaf(px, E02a,
                         __builtin_fmaf(py, E012b, -(pz * E01bf)));
        const float zy = __builtin_fmaf(px, E02b,
                         __builtin_fmaf(pz, E01af, -(py * E012a)));
        const float zz = __builtin_fmaf(px, E012d,
                         __builtin_fmaf(py, E12fh, pz * E1g));
        const float z1 = __builtin_fmaf(nx, zx,
                         __builtin_fmaf(ny, zy, nz * zz));

        out2[e ? b + H : b] = make_float2(__builtin_fmaf(z0, hw0, hw0),
                                          __builtin_fmaf(z1, hw1, hw1));
    }
}

extern "C" void kernel_launch(void* const* d_in, const int* in_sizes, int n_in,
                              void* d_out, int out_size, void* d_ws, size_t ws_size,
                              hipStream_t stream) {
    const float* x        = (const float*)d_in[0];
    const float* w_input  = (const float*)d_in[1];
    const float* weights  = (const float*)d_in[2];
    const float* w_output = (const float*)d_in[3];
    float* out = (float*)d_out;

    const int B = in_sizes[0] / 4;
    const int H = B >> 1;

    heaq_kernel<<<(H + 255) / 256, 256, 0, stream>>>(
        (const float4*)x, w_input, weights, w_output, (float2*)out, B);
}

// Round 9
// 72.756 us; speedup vs baseline: 1.2505x; 1.0036x over previous
//
#include <hip/hip_runtime.h>

// HEAQNetwork via full Heisenberg (Pauli) propagation — zero state evolution
// (derivation verified R6, absmax 0.25). R8b: 2 ADJACENT elements per thread
// (2b, 2b+1) so the two float2 outputs merge into one 16B store; input loads
// are 32B/lane contiguous (coalesced). Nontemporal hints via clang native
// vector type (HIP_vector_type not accepted by the builtin).

typedef float vfloat4 __attribute__((ext_vector_type(4)));

__device__ __forceinline__ float rdlane(float x, int l) {
    return __int_as_float(__builtin_amdgcn_readlane(__float_as_int(x), l));
}

__global__ __launch_bounds__(256) void heaq_kernel(
    const vfloat4* __restrict__ x4,
    const float*  __restrict__ w_input,
    const float*  __restrict__ weights,
    const float*  __restrict__ w_output,
    vfloat4*      __restrict__ out4,
    int H)   // H = B/2 threads
{
    const int lane = threadIdx.x & 63;

    // full-angle sincos of the 12 batch-uniform weights via lanes 0..11
    const float K2 = 0.15915494309189535f;  // 1/(2*pi)
    float wv  = weights[lane < 12 ? lane : 11];
    float rev = __builtin_amdgcn_fractf(wv * K2);
    float sn  = __builtin_amdgcn_sinf(rev);
    float cn  = __builtin_amdgcn_cosf(rev);

    const float sw00 = rdlane(sn, 0), cw00 = rdlane(cn, 0);
    const float sw01 = rdlane(sn, 1), cw01 = rdlane(cn, 1);
    const float sw02 = rdlane(sn, 2), cw02 = rdlane(cn, 2);
    const float sw03 = rdlane(sn, 3);
    const float sB0  = rdlane(sn, 4), cB0  = rdlane(cn, 4);
    const float sB1  = rdlane(sn, 5), cB1  = rdlane(cn, 5);
    const float sB2  = rdlane(sn, 6), cB2  = rdlane(cn, 6);
    const float sC0  = rdlane(sn, 8), cC0  = rdlane(cn, 8);
    const float sC1  = rdlane(sn, 9), cC1  = rdlane(cn, 9);

    const int b = blockIdx.x * 256 + threadIdx.x;
    if (b >= H) return;

    const float wi0 = w_input[0], wi1 = w_input[1];
    const float wi2 = w_input[2], wi3 = w_input[3];
    const float hw0 = 0.5f * w_output[0], hw1 = 0.5f * w_output[1];

    // two adjacent elements: issue both streaming loads up-front
    const vfloat4 xva = __builtin_nontemporal_load(&x4[2 * b]);
    const vfloat4 xvb = __builtin_nontemporal_load(&x4[2 * b + 1]);

    float zo[2][2];

#pragma unroll
    for (int e = 0; e < 2; ++e) {
        const vfloat4 xv = e ? xvb : xva;
        const float us[4] = {xv.x * wi0, xv.y * wi1, xv.z * wi2, xv.w * wi3};
        float ca[4], sa[4];
#pragma unroll
        for (int q = 0; q < 4; ++q) {
            float u = us[q];
            float r = __builtin_amdgcn_rsqf(__builtin_fmaf(u, u, 1.0f));
            ca[q] = r;
            sa[q] = u * r;
        }

        // Bloch vectors of chi_q = RY(w0q) RX(a_q) |0>
        const float s0x = sw00 * ca[0], s0y = -sa[0], s0z = cw00 * ca[0];
        const float s1x = sw01 * ca[1], s1y = -sa[1], s1z = cw01 * ca[1];
        const float s2x = sw02 * ca[2], s2y = -sa[2], s2z = cw02 * ca[2];
        const float s3x = sw03 * ca[3];

        // D rows (layer-2 conjugation) and n,p (layer 3)
        const float ax = cB0, ay = sB0 * sa[0], az = sB0 * ca[0];
        const float           by = ca[0],       bz = -sa[0];
        const float dx = -sB0, dy = cB0 * sa[0], dz = cB0 * ca[0];
        const float ex = cB1, ey = sB1 * sa[1], ez = sB1 * ca[1];
        const float           fy = ca[1],       fz = -sa[1];
        const float gx = -sB1, gy = cB1 * sa[1], gz = cB1 * ca[1];
        const float hx = cB2, hy = sB2 * sa[2], hz = sB2 * ca[2];
        const float nx = -sC0, ny = cC0 * sa[0], nz = cC0 * ca[0];
        const float px = -sC1, py = cC1 * sa[1], pz = cC1 * ca[1];

        // shared precomputes
        const float t01   = s0z * s1x;
        const float t0z1y = s0z * s1y;
        const float t0z1z = s0z * s1z;
        const float m1 = s2y * s3x, m2 = s2x * s3x, m3 = s2z * s3x;
        const float RCh = __builtin_fmaf(hy, m1, hz * s2z);
        const float RDh = hx * m2;
        const float hx3 = hx * s3x;
        const float q1t = __builtin_fmaf(hz, s2y, -(hy * m3));

        const float Aa = __builtin_fmaf(ax, s0x, ay * s0y);
        const float Ba = __builtin_fmaf(ax, s0y, -(ay * s0x));
        const float Ab = by * s0y;
        const float Bb = -(by * s0x);
        const float Ad = __builtin_fmaf(dx, s0x, dy * s0y);
        const float Bd = __builtin_fmaf(dx, s0y, -(dy * s0x));

        // z0 = E01(u, e) + nz * E0(d),  u = nx*a + ny*b
        const float ux = nx * ax;
        const float uy = __builtin_fmaf(nx, ay, ny * by);
        const float uz = __builtin_fmaf(nx, az, ny * bz);
        const float Au = __builtin_fmaf(ux, s0x, uy * s0y);
        const float Bu = __builtin_fmaf(ux, s0y, -(uy * s0x));
        const float E01u = (ex * s2x) * __builtin_fmaf(uz, t01, Au)
                         + (ey * s2x) * __builtin_fmaf(Bu, s1z, uz * s1y)
                         + ez * __builtin_fmaf(uz, s1z, -(Bu * s1y));
        const float E0d = __builtin_fmaf(Ad, s1x, dz * s0z);
        zo[e][0] = __builtin_fmaf(nz, E0d, E01u);

        // z1 pieces
        const float E02a = RCh * __builtin_fmaf(az, s1z, -(Ba * s1y))
                         + RDh * __builtin_fmaf(Aa, s1x, az * s0z);
        const float E02b = RCh * __builtin_fmaf(bz, s1z, -(Bb * s1y))
                         + RDh * __builtin_fmaf(Ab, s1x, bz * s0z);

        const float RAg = __builtin_fmaf(gx, hx3, gy * q1t);
        const float RBg = __builtin_fmaf(gy, hx3, -(gx * q1t));
        const float RCg = gz * RDh;
        const float RDg = gz * RCh;
        const float RAe = __builtin_fmaf(ex, hx3, ey * q1t);
        const float RBe = __builtin_fmaf(ey, hx3, -(ex * q1t));
        const float RCe = ez * RDh;
        const float RDe = ez * RCh;

        const float E012b = RAg * __builtin_fmaf(bz, t01, Ab)
                          + RBg * __builtin_fmaf(Bb, s1z, bz * s1y)
                          + RCg * __builtin_fmaf(bz, s1z, -(Bb * s1y))
                          + RDg * __builtin_fmaf(Ab, s1x, bz * s0z);
        const float E012a = RAg * __builtin_fmaf(az, t01, Aa)
                          + RBg * __builtin_fmaf(Ba, s1z, az * s1y)
                          + RCg * __builtin_fmaf(az, s1z, -(Ba * s1y))
                          + RDg * __builtin_fmaf(Aa, s1x, az * s0z);
        const float E012d = RAe * __builtin_fmaf(dz, t01, Ad)
                          + RBe * __builtin_fmaf(Bd, s1z, dz * s1y)
                          + RCe * __builtin_fmaf(dz, s1z, -(Bd * s1y))
                          + RDe * __builtin_fmaf(Ad, s1x, dz * s0z);

        const float fys2x = fy * s2x;
        const float E01bf = fys2x * __builtin_fmaf(Bb, s1z, bz * s1y)
                          + fz * __builtin_fmaf(bz, s1z, -(Bb * s1y));
        const float E01af = fys2x * __builtin_fmaf(Ba, s1z, az * s1y)
                          + fz * __builtin_fmaf(az, s1z, -(Ba * s1y));

        const float E12fh = (fy * q1t) * s1x + (fy * hx3) * t0z1y
                          + (fz * RDh) * t0z1z + fz * RCh;

        const float E1g = s2x * __builtin_fmaf(gx, s1x, gy * t0z1y)
                        + gz * t0z1z;

        const float zx = __builtin_fmaf(px, E02a,
                         __builtin_fmaf(py, E012b, -(pz * E01bf)));
        const float zy = __builtin_fmaf(px, E02b,
                         __builtin_fmaf(pz, E01af, -(py * E012a)));
        const float zz = __builtin_fmaf(px, E012d,
                         __builtin_fmaf(py, E12fh, pz * E1g));
        zo[e][1] = __builtin_fmaf(nx, zx, __builtin_fmaf(ny, zy, nz * zz));
    }

    vfloat4 o;
    o.x = __builtin_fmaf(zo[0][0], hw0, hw0);
    o.y = __builtin_fmaf(zo[0][1], hw1, hw1);
    o.z = __builtin_fmaf(zo[1][0], hw0, hw0);
    o.w = __builtin_fmaf(zo[1][1], hw1, hw1);
    __builtin_nontemporal_store(o, &out4[b]);
}

extern "C" void kernel_launch(void* const* d_in, const int* in_sizes, int n_in,
                              void* d_out, int out_size, void* d_ws, size_t ws_size,
                              hipStream_t stream) {
    const float* x        = (const float*)d_in[0];
    const float* w_input  = (const float*)d_in[1];
    const float* weights  = (const float*)d_in[2];
    const float* w_output = (const float*)d_in[3];
    float* out = (float*)d_out;

    const int B = in_sizes[0] / 4;
    const int H = B >> 1;

    heaq_kernel<<<(H + 255) / 256, 256, 0, stream>>>(
        (const vfloat4*)x, w_input, weights, w_output, (vfloat4*)out, H);
}